// Round 3
// baseline (2951.317 us; speedup 1.0000x reference)
//
#include <hip/hip_runtime.h>
#include <math.h>

#define N3 262144           // 64^3

// ---------------------------------------------------------------------------
// Lattice helper: emb row (4) and sh1 row (3) for tap p in [0,27)
// ---------------------------------------------------------------------------
__device__ inline void lattice_row(int p, float* embr, float* sh1r) {
    int i = p / 9, j = (p / 3) % 3, k = p % 3;
    float gx = (float)(i - 1), gy = (float)(j - 1), gz = (float)(k - 1);
    float r = sqrtf(gx * gx + gy * gy + gz * gz);
    float inv = (r > 0.f) ? (1.0f / fmaxf(r, 1e-9f)) : 0.f;
    const float s3 = 1.7320508075688772f;
    sh1r[0] = s3 * gx * inv;
    sh1r[1] = s3 * gy * inv;
    sh1r[2] = s3 * gz * inv;
    const float centers[4] = {0.f, 0.33333334f, 0.6666667f, 1.f};
    const float step = 0.33333334f;
    #pragma unroll
    for (int b = 0; b < 4; b++) {
        float dd = (r - centers[b]) / step;
        float e = 0.f;
        if (fabsf(dd) < 1.f)
            e = 1.14136f * expf(2.f) * expf(-1.f / fmaxf(1.f - dd * dd, 1e-9f));
        embr[b] = e;
    }
}

__device__ inline float eps3f(int m, int s, int n) {
    if (m == s || s == n || m == n) return 0.f;
    return ((m == 0 && s == 1 && n == 2) || (m == 1 && s == 2 && n == 0) ||
            (m == 2 && s == 0 && n == 1)) ? 1.f : -1.f;
}

// ---------------------------------------------------------------------------
// Build Km1 (27,8,48) and Km2 (27,40,48); one element per thread.
// ---------------------------------------------------------------------------
__global__ __launch_bounds__(256) void build_kernels_kernel(
        const float* __restrict__ w1,
        const float* __restrict__ w2,
        float* __restrict__ Km1,
        float* __restrict__ Km2) {
    const float inv_ks15 = 0.19245008972987526f;  // 1/3^1.5
    int gid = blockIdx.x * 256 + threadIdx.x;
    if (gid < 27 * 8 * 48) {
        int idx = gid;
        int p = idx / 384, rem = idx % 384, i = rem / 48, o = rem % 48;
        float embr[4], sh1r[3];
        lattice_row(p, embr, sh1r);
        const float a = 0.35355339059327373f;  // 1/sqrt(8)
        float val;
        int c;
        if (o < 16) c = i * 16 + o;
        else if (o < 24) c = 128 + i * 8 + (o - 16);
        else c = 192 + i * 8 + (o - 24) / 3;
        float W = 0.f;
        #pragma unroll
        for (int b = 0; b < 4; b++) W += embr[b] * w1[b * 256 + c];
        W *= inv_ks15;
        if (o < 24) val = a * W;
        else val = a * W * sh1r[(o - 24) % 3];
        Km1[idx] = val;
    } else if (gid < 27 * 8 * 48 + 27 * 40 * 48) {
        int idx = gid - 27 * 8 * 48;
        int p = idx / 1920, rem = idx % 1920, row = rem / 48, o = rem % 48;
        float embr[4], sh1r[3];
        lattice_row(p, embr, sh1r);
        auto Wat = [&](int c) -> float {
            float s = 0.f;
            #pragma unroll
            for (int b = 0; b < 4; b++) s += embr[b] * w2[b * 832 + c];
            return s * inv_ks15;
        };
        const float a_s = 0.2041241452319315f;   // 1/sqrt(24)
        const float a_v = 0.17677669529663687f;  // 1/sqrt(32)
        const float a_s3 = 0.11785113019775793f; // a_s/sqrt(3)
        const float a_v6 = 0.07216878364870322f; // a_v/sqrt(6)
        float val;
        if (row < 16) {
            int i = row;
            if (o < 16) val = a_s * Wat(i * 16 + o);
            else if (o < 24) val = a_s * Wat(256 + i * 8 + (o - 16));
            else {
                int jj = (o - 24) / 3, mo = (o - 24) % 3;
                val = a_v * Wat(384 + i * 8 + jj) * sh1r[mo];
            }
        } else {
            int u = (row - 16) / 3, m = (row - 16) % 3;
            if (o < 16) val = a_s3 * Wat(576 + u * 16 + o) * sh1r[m];
            else if (o < 24) val = a_s3 * Wat(704 + u * 8 + (o - 16)) * sh1r[m];
            else {
                int jj = (o - 24) / 3, n = (o - 24) % 3;
                float v0 = (m == n) ? a_v * Wat(512 + u * 8 + jj) : 0.f;
                float epssum = 0.f;
                #pragma unroll
                for (int s = 0; s < 3; s++) epssum += eps3f(m, s, n) * sh1r[s];
                val = v0 + a_v6 * Wat(768 + u * 8 + jj) * epssum;
            }
        }
        Km2[idx] = val;
    }
}

// 7 nonzero taps: center p=13, faces p=4(d-1),22(d+1),10(h-1),16(h+1),12(w-1),14(w+1)
__device__ __constant__ int c_taps[7] = {13, 4, 22, 10, 16, 12, 14};

// ---------------------------------------------------------------------------
// conv1: x(8,64^3) -> ypre(48,64^3). 2 points/thread (w-pairs).
// sc1 skip folded into center tap. Fused BN partial stats via atomicAdd.
// Block 256 threads -> (h:8, w:64) slab of one d. Grid 512 = 64d x 8.
// ---------------------------------------------------------------------------
__global__ __launch_bounds__(256, 2) void conv1_kernel(const float* __restrict__ x,
                                                       const float* __restrict__ Km1,
                                                       const float* __restrict__ sc1,
                                                       float* __restrict__ out,
                                                       float* __restrict__ stats) {
    __shared__ float km[7 * 8 * 48];     // 10.5 KB
    __shared__ float red[4][72];
    for (int t = threadIdx.x; t < 7 * 384; t += 256) {
        int tp = t / 384, r = t % 384, i = r / 48, o = r % 48;
        float v = Km1[c_taps[tp] * 384 + r];
        if (tp == 0 && o < 24) v += 0.35355339059327373f * sc1[i * 24 + o];
        km[t] = v;
    }
    __syncthreads();

    int bx = blockIdx.x;
    int d = bx >> 3;
    int h = ((bx & 7) << 3) + (threadIdx.x >> 5);
    int w0 = (threadIdx.x & 31) * 2;
    int idx = (d << 12) + (h << 6) + w0;

    float acc0[48], acc1[48];
    #pragma unroll
    for (int o = 0; o < 48; o++) { acc0[o] = 0.f; acc1[o] = 0.f; }

    // fused taps: center(0), w-1(5), w+1(6)
    {
        const float* k0 = km;
        const float* k5 = km + 5 * 384;
        const float* k6 = km + 6 * 384;
        #pragma unroll
        for (int i = 0; i < 8; i++) {
            float2 c = *(const float2*)(x + i * N3 + idx);
            float eL = (w0 > 0) ? x[i * N3 + idx - 1] : 0.f;
            float eR = (w0 < 62) ? x[i * N3 + idx + 2] : 0.f;
            const float* kr0 = k0 + i * 48;
            const float* kr5 = k5 + i * 48;
            const float* kr6 = k6 + i * 48;
            #pragma unroll
            for (int o = 0; o < 48; o++) {
                acc0[o] += c.x * kr0[o] + eL * kr5[o] + c.y * kr6[o];
                acc1[o] += c.y * kr0[o] + c.x * kr5[o] + eR * kr6[o];
            }
        }
    }
    // plane taps: d-1(1), d+1(2), h-1(3), h+1(4)
    const int poff[4] = {-4096, 4096, -64, 64};
    #pragma unroll
    for (int t = 0; t < 4; t++) {
        bool ok = (t == 0) ? (d > 0) : (t == 1) ? (d < 63) : (t == 2) ? (h > 0) : (h < 63);
        if (ok) {
            int nidx = idx + poff[t];
            const float* kmt = km + (t + 1) * 384;
            #pragma unroll
            for (int i = 0; i < 8; i++) {
                float2 v = *(const float2*)(x + i * N3 + nidx);
                const float* kr = kmt + i * 48;
                #pragma unroll
                for (int o = 0; o < 48; o++) {
                    acc0[o] += v.x * kr[o];
                    acc1[o] += v.y * kr[o];
                }
            }
        }
    }
    #pragma unroll
    for (int o = 0; o < 48; o++) {
        float2 st = make_float2(acc0[o], acc1[o]);
        *(float2*)(out + o * N3 + idx) = st;
    }

    // fused BN partial stats: q<24: sum(ch q); q in [24,72): sumsq(ch q-24)
    int lane = threadIdx.x & 63, wv = threadIdx.x >> 6;
    #pragma unroll
    for (int q = 0; q < 72; q++) {
        float val;
        if (q < 24) val = acc0[q] + acc1[q];
        else { int c = q - 24; val = acc0[c] * acc0[c] + acc1[c] * acc1[c]; }
        #pragma unroll
        for (int m = 32; m >= 1; m >>= 1) val += __shfl_xor(val, m, 64);
        if (lane == 0) red[wv][q] = val;
    }
    __syncthreads();
    if (threadIdx.x < 72) {
        float s = red[0][threadIdx.x] + red[1][threadIdx.x] +
                  red[2][threadIdx.x] + red[3][threadIdx.x];
        atomicAdd(&stats[threadIdx.x], s);
    }
}

// ---------------------------------------------------------------------------
// conv2: y(40,64^3) -> zpre(48,64^3). Same structure; sc2_s/sc2_v folded into
// center tap; fused BN partial stats.
// ---------------------------------------------------------------------------
__global__ __launch_bounds__(256, 2) void conv2_kernel(const float* __restrict__ y,
                                                       const float* __restrict__ Km2,
                                                       const float* __restrict__ sc2s,
                                                       const float* __restrict__ sc2v,
                                                       float* __restrict__ out,
                                                       float* __restrict__ stats) {
    __shared__ float km[7 * 40 * 48];    // 52.5 KB
    __shared__ float red[4][72];
    for (int t = threadIdx.x; t < 7 * 1920; t += 256) {
        int tp = t / 1920, r = t % 1920, i = r / 48, o = r % 48;
        float v = Km2[c_taps[tp] * 1920 + r];
        if (tp == 0) {
            if (i < 16 && o < 24) {
                v += 0.25f * sc2s[i * 24 + o];
            } else if (i >= 16 && o >= 24) {
                int u = (i - 16) / 3, m = (i - 16) % 3;
                int jj = (o - 24) / 3, n = (o - 24) % 3;
                if (m == n) v += 0.35355339059327373f * sc2v[u * 8 + jj];
            }
        }
        km[t] = v;
    }
    __syncthreads();

    int bx = blockIdx.x;
    int d = bx >> 3;
    int h = ((bx & 7) << 3) + (threadIdx.x >> 5);
    int w0 = (threadIdx.x & 31) * 2;
    int idx = (d << 12) + (h << 6) + w0;

    float acc0[48], acc1[48];
    #pragma unroll
    for (int o = 0; o < 48; o++) { acc0[o] = 0.f; acc1[o] = 0.f; }

    // fused taps: center(0), w-1(5), w+1(6)
    {
        const float* k0 = km;
        const float* k5 = km + 5 * 1920;
        const float* k6 = km + 6 * 1920;
        #pragma unroll
        for (int i = 0; i < 40; i++) {
            float2 c = *(const float2*)(y + i * N3 + idx);
            float eL = (w0 > 0) ? y[i * N3 + idx - 1] : 0.f;
            float eR = (w0 < 62) ? y[i * N3 + idx + 2] : 0.f;
            const float* kr0 = k0 + i * 48;
            const float* kr5 = k5 + i * 48;
            const float* kr6 = k6 + i * 48;
            #pragma unroll
            for (int o = 0; o < 48; o++) {
                acc0[o] += c.x * kr0[o] + eL * kr5[o] + c.y * kr6[o];
                acc1[o] += c.y * kr0[o] + c.x * kr5[o] + eR * kr6[o];
            }
        }
    }
    // plane taps: d-1(1), d+1(2), h-1(3), h+1(4)
    const int poff[4] = {-4096, 4096, -64, 64};
    #pragma unroll
    for (int t = 0; t < 4; t++) {
        bool ok = (t == 0) ? (d > 0) : (t == 1) ? (d < 63) : (t == 2) ? (h > 0) : (h < 63);
        if (ok) {
            int nidx = idx + poff[t];
            const float* kmt = km + (t + 1) * 1920;
            #pragma unroll
            for (int i = 0; i < 40; i++) {
                float2 v = *(const float2*)(y + i * N3 + nidx);
                const float* kr = kmt + i * 48;
                #pragma unroll
                for (int o = 0; o < 48; o++) {
                    acc0[o] += v.x * kr[o];
                    acc1[o] += v.y * kr[o];
                }
            }
        }
    }
    #pragma unroll
    for (int o = 0; o < 48; o++) {
        float2 st = make_float2(acc0[o], acc1[o]);
        *(float2*)(out + o * N3 + idx) = st;
    }

    int lane = threadIdx.x & 63, wv = threadIdx.x >> 6;
    #pragma unroll
    for (int q = 0; q < 72; q++) {
        float val;
        if (q < 24) val = acc0[q] + acc1[q];
        else { int c = q - 24; val = acc0[c] * acc0[c] + acc1[c] * acc1[c]; }
        #pragma unroll
        for (int m = 32; m >= 1; m >>= 1) val += __shfl_xor(val, m, 64);
        if (lane == 0) red[wv][q] = val;
    }
    __syncthreads();
    if (threadIdx.x < 72) {
        float s = red[0][threadIdx.x] + red[1][threadIdx.x] +
                  red[2][threadIdx.x] + red[3][threadIdx.x];
        atomicAdd(&stats[threadIdx.x], s);
    }
}

// ---------------------------------------------------------------------------
// Finalize BN stats from atomically-accumulated stats[72]:
// sb[0:24]=scaleS, sb[24:48]=biasS, sb[48:56]=scaleV
// ---------------------------------------------------------------------------
__global__ void finalize_kernel(const float* __restrict__ stats,
                                const float* __restrict__ wsc,
                                const float* __restrict__ bsc,
                                const float* __restrict__ wvc,
                                float* __restrict__ sb) {
    int t = threadIdx.x;
    const float invN = 1.0f / 262144.0f;
    if (t < 24) {
        float mu = stats[t] * invN;
        float var = stats[24 + t] * invN - mu * mu;
        float inv = rsqrtf(var + 1e-5f);
        sb[t] = wsc[t] * inv;
        sb[24 + t] = bsc[t] - mu * wsc[t] * inv;
    } else if (t < 32) {
        int u = t - 24;
        float s2 = stats[48 + u * 3] + stats[48 + u * 3 + 1] + stats[48 + u * 3 + 2];
        sb[48 + u] = wvc[u] * rsqrtf(s2 * invN + 1e-5f);
    }
}

// ---------------------------------------------------------------------------
// BN apply + gate: zp(48ch) -> out(40ch), float2 per thread
// ---------------------------------------------------------------------------
__global__ __launch_bounds__(256) void bn_gate_kernel(const float* __restrict__ zp,
                                                      const float* __restrict__ sb,
                                                      float* __restrict__ out) {
    int gid = blockIdx.x * 256 + threadIdx.x;
    int idx = gid * 2;
    float gx[8], gy[8];
    #pragma unroll
    for (int u = 0; u < 8; u++) {
        float2 v = *(const float2*)(zp + (16 + u) * N3 + idx);
        float ax = v.x * sb[16 + u] + sb[40 + u];
        float ay = v.y * sb[16 + u] + sb[40 + u];
        gx[u] = 1.0f / (1.0f + expf(-ax));
        gy[u] = 1.0f / (1.0f + expf(-ay));
    }
    #pragma unroll
    for (int c = 0; c < 16; c++) {
        float2 v = *(const float2*)(zp + c * N3 + idx);
        float2 r;
        r.x = fmaxf(v.x * sb[c] + sb[24 + c], 0.f);
        r.y = fmaxf(v.y * sb[c] + sb[24 + c], 0.f);
        *(float2*)(out + c * N3 + idx) = r;
    }
    #pragma unroll
    for (int u = 0; u < 8; u++) {
        float sv = sb[48 + u];
        #pragma unroll
        for (int m = 0; m < 3; m++) {
            float2 v = *(const float2*)(zp + (24 + u * 3 + m) * N3 + idx);
            float2 r;
            r.x = v.x * sv * gx[u];
            r.y = v.y * sv * gy[u];
            *(float2*)(out + (16 + u * 3 + m) * N3 + idx) = r;
        }
    }
}

// ---------------------------------------------------------------------------
extern "C" void kernel_launch(void* const* d_in, const int* in_sizes, int n_in,
                              void* d_out, int out_size, void* d_ws, size_t ws_size,
                              hipStream_t stream) {
    const float* x      = (const float*)d_in[0];
    const float* w1     = (const float*)d_in[1];
    const float* sc1    = (const float*)d_in[2];
    const float* w2     = (const float*)d_in[3];
    const float* sc2s   = (const float*)d_in[4];
    const float* sc2v   = (const float*)d_in[5];
    const float* bn1_ws = (const float*)d_in[6];
    const float* bn1_bs = (const float*)d_in[7];
    const float* bn1_wv = (const float*)d_in[8];
    const float* bn2_ws = (const float*)d_in[9];
    const float* bn2_bs = (const float*)d_in[10];
    const float* bn2_wv = (const float*)d_in[11];
    float* out = (float*)d_out;
    char* ws = (char*)d_ws;

    float* Km1    = (float*)(ws + 0);        // 41472 B
    float* Km2    = (float*)(ws + 41472);    // 207360 B
    float* stats1 = (float*)(ws + 248832);   // 288 B
    float* stats2 = (float*)(ws + 249120);   // 288 B
    float* sb1    = (float*)(ws + 249408);   // 224 B
    float* sb2    = (float*)(ws + 249664);   // 224 B
    float* bufA   = (float*)(ws + 262144);   // 48*N3*4 = 50331648 B

    hipMemsetAsync(ws + 248832, 0, 2 * 72 * 4, stream);
    hipLaunchKernelGGL(build_kernels_kernel, dim3(243), dim3(256), 0, stream, w1, w2, Km1, Km2);
    hipLaunchKernelGGL(conv1_kernel, dim3(512), dim3(256), 0, stream, x, Km1, sc1, bufA, stats1);
    hipLaunchKernelGGL(finalize_kernel, dim3(1), dim3(32), 0, stream, stats1, bn1_ws, bn1_bs, bn1_wv, sb1);
    hipLaunchKernelGGL(bn_gate_kernel, dim3(512), dim3(256), 0, stream, bufA, sb1, out);
    hipLaunchKernelGGL(conv2_kernel, dim3(512), dim3(256), 0, stream, out, Km2, sc2s, sc2v, bufA, stats2);
    hipLaunchKernelGGL(finalize_kernel, dim3(1), dim3(32), 0, stream, stats2, bn2_ws, bn2_bs, bn2_wv, sb2);
    hipLaunchKernelGGL(bn_gate_kernel, dim3(512), dim3(256), 0, stream, bufA, sb2, out);
}

// Round 4
// 323.460 us; speedup vs baseline: 9.1242x; 9.1242x over previous
//
#include <hip/hip_runtime.h>
#include <math.h>

#define N3 262144           // 64^3

// ---------------------------------------------------------------------------
// Lattice helper: emb row (4) and sh1 row (3) for tap p in [0,27)
// ---------------------------------------------------------------------------
__device__ inline void lattice_row(int p, float* embr, float* sh1r) {
    int i = p / 9, j = (p / 3) % 3, k = p % 3;
    float gx = (float)(i - 1), gy = (float)(j - 1), gz = (float)(k - 1);
    float r = sqrtf(gx * gx + gy * gy + gz * gz);
    float inv = (r > 0.f) ? (1.0f / fmaxf(r, 1e-9f)) : 0.f;
    const float s3 = 1.7320508075688772f;
    sh1r[0] = s3 * gx * inv;
    sh1r[1] = s3 * gy * inv;
    sh1r[2] = s3 * gz * inv;
    const float centers[4] = {0.f, 0.33333334f, 0.6666667f, 1.f};
    const float step = 0.33333334f;
    #pragma unroll
    for (int b = 0; b < 4; b++) {
        float dd = (r - centers[b]) / step;
        float e = 0.f;
        if (fabsf(dd) < 1.f)
            e = 1.14136f * expf(2.f) * expf(-1.f / fmaxf(1.f - dd * dd, 1e-9f));
        embr[b] = e;
    }
}

__device__ inline float eps3f(int m, int s, int n) {
    if (m == s || s == n || m == n) return 0.f;
    return ((m == 0 && s == 1 && n == 2) || (m == 1 && s == 2 && n == 0) ||
            (m == 2 && s == 0 && n == 1)) ? 1.f : -1.f;
}

// ---------------------------------------------------------------------------
// Build Km1 (27,8,48) and Km2 (27,40,48); one element per thread.
// ---------------------------------------------------------------------------
__global__ __launch_bounds__(256) void build_kernels_kernel(
        const float* __restrict__ w1,
        const float* __restrict__ w2,
        float* __restrict__ Km1,
        float* __restrict__ Km2) {
    const float inv_ks15 = 0.19245008972987526f;  // 1/3^1.5
    int gid = blockIdx.x * 256 + threadIdx.x;
    if (gid < 27 * 8 * 48) {
        int idx = gid;
        int p = idx / 384, rem = idx % 384, i = rem / 48, o = rem % 48;
        float embr[4], sh1r[3];
        lattice_row(p, embr, sh1r);
        const float a = 0.35355339059327373f;  // 1/sqrt(8)
        float val;
        int c;
        if (o < 16) c = i * 16 + o;
        else if (o < 24) c = 128 + i * 8 + (o - 16);
        else c = 192 + i * 8 + (o - 24) / 3;
        float W = 0.f;
        #pragma unroll
        for (int b = 0; b < 4; b++) W += embr[b] * w1[b * 256 + c];
        W *= inv_ks15;
        if (o < 24) val = a * W;
        else val = a * W * sh1r[(o - 24) % 3];
        Km1[idx] = val;
    } else if (gid < 27 * 8 * 48 + 27 * 40 * 48) {
        int idx = gid - 27 * 8 * 48;
        int p = idx / 1920, rem = idx % 1920, row = rem / 48, o = rem % 48;
        float embr[4], sh1r[3];
        lattice_row(p, embr, sh1r);
        auto Wat = [&](int c) -> float {
            float s = 0.f;
            #pragma unroll
            for (int b = 0; b < 4; b++) s += embr[b] * w2[b * 832 + c];
            return s * inv_ks15;
        };
        const float a_s = 0.2041241452319315f;   // 1/sqrt(24)
        const float a_v = 0.17677669529663687f;  // 1/sqrt(32)
        const float a_s3 = 0.11785113019775793f; // a_s/sqrt(3)
        const float a_v6 = 0.07216878364870322f; // a_v/sqrt(6)
        float val;
        if (row < 16) {
            int i = row;
            if (o < 16) val = a_s * Wat(i * 16 + o);
            else if (o < 24) val = a_s * Wat(256 + i * 8 + (o - 16));
            else {
                int jj = (o - 24) / 3, mo = (o - 24) % 3;
                val = a_v * Wat(384 + i * 8 + jj) * sh1r[mo];
            }
        } else {
            int u = (row - 16) / 3, m = (row - 16) % 3;
            if (o < 16) val = a_s3 * Wat(576 + u * 16 + o) * sh1r[m];
            else if (o < 24) val = a_s3 * Wat(704 + u * 8 + (o - 16)) * sh1r[m];
            else {
                int jj = (o - 24) / 3, n = (o - 24) % 3;
                float v0 = (m == n) ? a_v * Wat(512 + u * 8 + jj) : 0.f;
                float epssum = 0.f;
                #pragma unroll
                for (int s = 0; s < 3; s++) epssum += eps3f(m, s, n) * sh1r[s];
                val = v0 + a_v6 * Wat(768 + u * 8 + jj) * epssum;
            }
        }
        Km2[idx] = val;
    }
}

// tap order t: 0=center(p13), 1=d-1(p4), 2=d+1(p22), 3=h-1(p10), 4=h+1(p16),
//              5=w-1(p12), 6=w+1(p14)
__device__ __constant__ int c_taps[7] = {13, 4, 22, 10, 16, 12, 14};

// ---------------------------------------------------------------------------
// conv1: x(8,64^3) -> ypre(48,64^3). 1 pt/thread, streaming taps,
// sc1 folded into center tap, fused BN partial stats.
// ---------------------------------------------------------------------------
__global__ __launch_bounds__(256) void conv1_kernel(const float* __restrict__ x,
                                                    const float* __restrict__ Km1,
                                                    const float* __restrict__ sc1,
                                                    float* __restrict__ out,
                                                    float* __restrict__ stats) {
    __shared__ float km[7 * 384];     // 10.5 KB
    __shared__ float red[4][72];
    for (int t = threadIdx.x; t < 7 * 384; t += 256) {
        int tp = t / 384, r = t % 384, i = r / 48, o = r % 48;
        float v = Km1[c_taps[tp] * 384 + r];
        if (tp == 0 && o < 24) v += 0.35355339059327373f * sc1[i * 24 + o];
        km[t] = v;
    }
    __syncthreads();

    int idx = blockIdx.x * 256 + threadIdx.x;
    int w = idx & 63, h = (idx >> 6) & 63, d = idx >> 12;

    float acc[48];
    #pragma unroll
    for (int o = 0; o < 48; o++) acc[o] = 0.f;

    const int offs[7] = {0, -4096, 4096, -64, 64, -1, 1};
    #pragma unroll
    for (int t = 0; t < 7; t++) {
        bool ok = (t == 0) ||
                  (t == 1 && d > 0) || (t == 2 && d < 63) ||
                  (t == 3 && h > 0) || (t == 4 && h < 63) ||
                  (t == 5 && w > 0) || (t == 6 && w < 63);
        if (!ok) continue;
        int nidx = idx + offs[t];
        const float* kmt = km + t * 384;
        #pragma unroll
        for (int i = 0; i < 8; i++) {
            float v = x[i * N3 + nidx];
            const float* kr = kmt + i * 48;
            #pragma unroll
            for (int o = 0; o < 48; o++) acc[o] += v * kr[o];
        }
    }
    #pragma unroll
    for (int o = 0; o < 48; o++) out[o * N3 + idx] = acc[o];

    // fused BN partial stats: q<24 -> sum(ch q); q in [24,72) -> sumsq(ch q-24)
    int lane = threadIdx.x & 63, wv = threadIdx.x >> 6;
    #pragma unroll
    for (int q = 0; q < 72; q++) {
        float val = (q < 24) ? acc[q] : acc[q - 24] * acc[q - 24];
        #pragma unroll
        for (int m = 32; m >= 1; m >>= 1) val += __shfl_xor(val, m, 64);
        if (lane == 0) red[wv][q] = val;
    }
    __syncthreads();
    if (threadIdx.x < 72) {
        float s = red[0][threadIdx.x] + red[1][threadIdx.x] +
                  red[2][threadIdx.x] + red[3][threadIdx.x];
        atomicAdd(&stats[threadIdx.x], s);
    }
}

// ---------------------------------------------------------------------------
// conv2: y(40,64^3) -> zpre(48,64^3). Output channels split across
// blockIdx.y (24 each) -> acc[24], km LDS 26.25 KB -> 5 blocks/CU.
// sc2_s / sc2_v folded into center tap. Fused BN partial stats.
// ---------------------------------------------------------------------------
__global__ __launch_bounds__(256) void conv2_kernel(const float* __restrict__ y,
                                                    const float* __restrict__ Km2,
                                                    const float* __restrict__ sc2s,
                                                    const float* __restrict__ sc2v,
                                                    float* __restrict__ out,
                                                    float* __restrict__ stats) {
    const int ohalf = blockIdx.y;
    const int obase = ohalf * 24;
    __shared__ float km[7 * 40 * 24];   // 26.25 KB
    __shared__ float red[4][48];
    for (int t = threadIdx.x; t < 7 * 960; t += 256) {
        int tp = t / 960, r = t % 960, i = r / 24, o24 = r % 24;
        int og = obase + o24;
        float v = Km2[c_taps[tp] * 1920 + i * 48 + og];
        if (tp == 0) {
            if (ohalf == 0) {
                if (i < 16) v += 0.25f * sc2s[i * 24 + og];
            } else {
                if (i >= 16) {
                    int u = (i - 16) / 3, m = (i - 16) % 3;
                    int jj = (og - 24) / 3, n = (og - 24) % 3;
                    if (m == n) v += 0.35355339059327373f * sc2v[u * 8 + jj];
                }
            }
        }
        km[tp * 960 + i * 24 + o24] = v;
    }
    __syncthreads();

    int idx = blockIdx.x * 256 + threadIdx.x;
    int w = idx & 63, h = (idx >> 6) & 63, d = idx >> 12;

    float acc[24];
    #pragma unroll
    for (int o = 0; o < 24; o++) acc[o] = 0.f;

    const int offs[7] = {0, -4096, 4096, -64, 64, -1, 1};
    #pragma unroll
    for (int t = 0; t < 7; t++) {
        bool ok = (t == 0) ||
                  (t == 1 && d > 0) || (t == 2 && d < 63) ||
                  (t == 3 && h > 0) || (t == 4 && h < 63) ||
                  (t == 5 && w > 0) || (t == 6 && w < 63);
        if (!ok) continue;
        int nidx = idx + offs[t];
        const float* kmt = km + t * 960;
        #pragma unroll
        for (int i = 0; i < 40; i++) {
            float v = y[i * N3 + nidx];
            const float* kr = kmt + i * 24;
            #pragma unroll
            for (int o = 0; o < 24; o++) acc[o] += v * kr[o];
        }
    }
    #pragma unroll
    for (int o = 0; o < 24; o++) out[(obase + o) * N3 + idx] = acc[o];

    // fused BN partial stats
    int lane = threadIdx.x & 63, wv = threadIdx.x >> 6;
    if (ohalf == 0) {
        // q<24: sum(ch q); q in [24,48): sumsq(ch q-24)
        #pragma unroll
        for (int q = 0; q < 48; q++) {
            float val = (q < 24) ? acc[q] : acc[q - 24] * acc[q - 24];
            #pragma unroll
            for (int m = 32; m >= 1; m >>= 1) val += __shfl_xor(val, m, 64);
            if (lane == 0) red[wv][q] = val;
        }
        __syncthreads();
        if (threadIdx.x < 48) {
            float s = red[0][threadIdx.x] + red[1][threadIdx.x] +
                      red[2][threadIdx.x] + red[3][threadIdx.x];
            atomicAdd(&stats[threadIdx.x], s);
        }
    } else {
        // sumsq of channels 24..47 -> stats[48+q]
        #pragma unroll
        for (int q = 0; q < 24; q++) {
            float val = acc[q] * acc[q];
            #pragma unroll
            for (int m = 32; m >= 1; m >>= 1) val += __shfl_xor(val, m, 64);
            if (lane == 0) red[wv][q] = val;
        }
        __syncthreads();
        if (threadIdx.x < 24) {
            float s = red[0][threadIdx.x] + red[1][threadIdx.x] +
                      red[2][threadIdx.x] + red[3][threadIdx.x];
            atomicAdd(&stats[48 + threadIdx.x], s);
        }
    }
}

// ---------------------------------------------------------------------------
// Finalize BN stats from stats[72]:
// sb[0:24]=scaleS, sb[24:48]=biasS, sb[48:56]=scaleV
// ---------------------------------------------------------------------------
__global__ void finalize_kernel(const float* __restrict__ stats,
                                const float* __restrict__ wsc,
                                const float* __restrict__ bsc,
                                const float* __restrict__ wvc,
                                float* __restrict__ sb) {
    int t = threadIdx.x;
    const float invN = 1.0f / 262144.0f;
    if (t < 24) {
        float mu = stats[t] * invN;
        float var = stats[24 + t] * invN - mu * mu;
        float inv = rsqrtf(var + 1e-5f);
        sb[t] = wsc[t] * inv;
        sb[24 + t] = bsc[t] - mu * wsc[t] * inv;
    } else if (t < 32) {
        int u = t - 24;
        float s2 = stats[48 + u * 3] + stats[48 + u * 3 + 1] + stats[48 + u * 3 + 2];
        sb[48 + u] = wvc[u] * rsqrtf(s2 * invN + 1e-5f);
    }
}

// ---------------------------------------------------------------------------
// BN apply + gate: zp(48ch) -> out(40ch), float4 per thread
// ---------------------------------------------------------------------------
__global__ __launch_bounds__(256) void bn_gate_kernel(const float* __restrict__ zp,
                                                      const float* __restrict__ sb,
                                                      float* __restrict__ out) {
    int idx = (blockIdx.x * 256 + threadIdx.x) * 4;
    float4 g[8];
    #pragma unroll
    for (int u = 0; u < 8; u++) {
        float4 v = *(const float4*)(zp + (16 + u) * N3 + idx);
        float sc = sb[16 + u], bi = sb[40 + u];
        g[u].x = 1.0f / (1.0f + expf(-(v.x * sc + bi)));
        g[u].y = 1.0f / (1.0f + expf(-(v.y * sc + bi)));
        g[u].z = 1.0f / (1.0f + expf(-(v.z * sc + bi)));
        g[u].w = 1.0f / (1.0f + expf(-(v.w * sc + bi)));
    }
    #pragma unroll
    for (int c = 0; c < 16; c++) {
        float4 v = *(const float4*)(zp + c * N3 + idx);
        float sc = sb[c], bi = sb[24 + c];
        float4 r;
        r.x = fmaxf(v.x * sc + bi, 0.f);
        r.y = fmaxf(v.y * sc + bi, 0.f);
        r.z = fmaxf(v.z * sc + bi, 0.f);
        r.w = fmaxf(v.w * sc + bi, 0.f);
        *(float4*)(out + c * N3 + idx) = r;
    }
    #pragma unroll
    for (int u = 0; u < 8; u++) {
        float sv = sb[48 + u];
        #pragma unroll
        for (int m = 0; m < 3; m++) {
            float4 v = *(const float4*)(zp + (24 + u * 3 + m) * N3 + idx);
            float4 r;
            r.x = v.x * sv * g[u].x;
            r.y = v.y * sv * g[u].y;
            r.z = v.z * sv * g[u].z;
            r.w = v.w * sv * g[u].w;
            *(float4*)(out + (16 + u * 3 + m) * N3 + idx) = r;
        }
    }
}

// ---------------------------------------------------------------------------
extern "C" void kernel_launch(void* const* d_in, const int* in_sizes, int n_in,
                              void* d_out, int out_size, void* d_ws, size_t ws_size,
                              hipStream_t stream) {
    const float* x      = (const float*)d_in[0];
    const float* w1     = (const float*)d_in[1];
    const float* sc1    = (const float*)d_in[2];
    const float* w2     = (const float*)d_in[3];
    const float* sc2s   = (const float*)d_in[4];
    const float* sc2v   = (const float*)d_in[5];
    const float* bn1_ws = (const float*)d_in[6];
    const float* bn1_bs = (const float*)d_in[7];
    const float* bn1_wv = (const float*)d_in[8];
    const float* bn2_ws = (const float*)d_in[9];
    const float* bn2_bs = (const float*)d_in[10];
    const float* bn2_wv = (const float*)d_in[11];
    float* out = (float*)d_out;
    char* ws = (char*)d_ws;

    float* Km1    = (float*)(ws + 0);        // 41472 B
    float* Km2    = (float*)(ws + 41472);    // 207360 B
    float* stats1 = (float*)(ws + 248832);   // 288 B
    float* stats2 = (float*)(ws + 249120);   // 288 B
    float* sb1    = (float*)(ws + 249408);   // 224 B
    float* sb2    = (float*)(ws + 249664);   // 224 B
    float* bufA   = (float*)(ws + 262144);   // 48*N3*4 = 50331648 B

    hipMemsetAsync(ws + 248832, 0, 2 * 72 * 4, stream);
    hipLaunchKernelGGL(build_kernels_kernel, dim3(243), dim3(256), 0, stream, w1, w2, Km1, Km2);
    hipLaunchKernelGGL(conv1_kernel, dim3(1024), dim3(256), 0, stream, x, Km1, sc1, bufA, stats1);
    hipLaunchKernelGGL(finalize_kernel, dim3(1), dim3(32), 0, stream, stats1, bn1_ws, bn1_bs, bn1_wv, sb1);
    hipLaunchKernelGGL(bn_gate_kernel, dim3(256), dim3(256), 0, stream, bufA, sb1, out);
    hipLaunchKernelGGL(conv2_kernel, dim3(1024, 2), dim3(256), 0, stream, out, Km2, sc2s, sc2v, bufA, stats2);
    hipLaunchKernelGGL(finalize_kernel, dim3(1), dim3(32), 0, stream, stats2, bn2_ws, bn2_bs, bn2_wv, sb2);
    hipLaunchKernelGGL(bn_gate_kernel, dim3(256), dim3(256), 0, stream, bufA, sb2, out);
}